// Round 1
// 1043.726 us; speedup vs baseline: 1.1824x; 1.1824x over previous
//
#include <hip/hip_runtime.h>

typedef _Float16 half8_t __attribute__((ext_vector_type(8)));
typedef _Float16 half4_t __attribute__((ext_vector_type(4)));
typedef float    f32x4   __attribute__((ext_vector_type(4)));

#define BSZ 32
#define SEQ 256
#define DD  128
#define MAT 16384   // 128*128
#define NCH 16      // chunks per sequence
#define CL  16      // chunk length

// ---- swizzled LDS layout: 128 rows x 16 chunks of 16B (8 f16). chunk j of row m
// stored at physical chunk (j ^ (m&7)).
__device__ __forceinline__ int sw_chunk(int m, int kb) { return (m << 4) + (kb ^ (m & 7)); }
__device__ __forceinline__ int sw_off(int m, int k)    { return (sw_chunk(m, k >> 3) << 3) + (k & 7); }

// ---- raw barriers WITHOUT the vmcnt(0) drain __syncthreads() forces.
// lgkmcnt(0) makes this wave's LDS writes visible; s_barrier syncs; global
// prefetch loads stay in flight across the barrier (compiler tracks their
// register deps and waits precisely at first use).
__device__ __forceinline__ void barrier_lgkm() {
  asm volatile("s_waitcnt lgkmcnt(0)" ::: "memory");
  __builtin_amdgcn_s_barrier();
  asm volatile("" ::: "memory");
}
__device__ __forceinline__ void barrier_only() {
  asm volatile("" ::: "memory");
  __builtin_amdgcn_s_barrier();
  asm volatile("" ::: "memory");
}

// 128x128x128 f16 matmul, fp32 acc. Ads: [m][k] k-contig (swizzled).
// Bds: row n holds column n of the B operand, k contiguous (swizzled).
// D[m][n] = sum_k Ads[m][k] * Bds_row_n[k].
__device__ __forceinline__ void mm128(const _Float16* __restrict__ Ads,
                                      const _Float16* __restrict__ Bds,
                                      f32x4 acc[4][4],
                                      int qr, int qc, int quad, int l16) {
#pragma unroll
  for (int ks = 0; ks < 4; ++ks) {
    const int kb = ks * 4 + quad;
    half8_t a[4], b[4];
#pragma unroll
    for (int tr = 0; tr < 4; ++tr)
      a[tr] = *(const half8_t*)&Ads[sw_chunk(qr * 64 + tr * 16 + l16, kb) << 3];
#pragma unroll
    for (int tc = 0; tc < 4; ++tc)
      b[tc] = *(const half8_t*)&Bds[sw_chunk(qc * 64 + tc * 16 + l16, kb) << 3];
#pragma unroll
    for (int tr = 0; tr < 4; ++tr)
#pragma unroll
      for (int tc = 0; tc < 4; ++tc)
        acc[tr][tc] = __builtin_amdgcn_mfma_f32_16x16x32_f16(a[tr], b[tc], acc[tr][tc], 0, 0, 0);
  }
}

// ---- transpose-pattern staging, f32 source (phase 1) ------------------------
// thread owns 4 blocks of 4x4: rows k0..k0+3 = (rowg0+p*8)*4.., cols colg*4..+3
__device__ __forceinline__ void tl_f32(const float* __restrict__ src, f32x4 ra[16],
                                       int colg, int rowg0) {
#pragma unroll
  for (int p = 0; p < 4; ++p)
#pragma unroll
    for (int j = 0; j < 4; ++j)
      ra[p * 4 + j] = *(const f32x4*)&src[(((rowg0 + p * 8) << 2) + j) * DD + (colg << 2)];
}
// write M^T into Ads: Ads row n (= col n of M), k contiguous. 16x ds_write_b64.
__device__ __forceinline__ void tw_f32(_Float16* Ads, const f32x4 ra[16],
                                       int colg, int rowg0) {
#pragma unroll
  for (int p = 0; p < 4; ++p) {
    const int k0 = (rowg0 + p * 8) << 2;
    const int kb = k0 >> 3, kpar = k0 & 7;
#pragma unroll
    for (int jj = 0; jj < 4; ++jj) {
      const int n = (colg << 2) + jj;
      half4_t hv;
      hv[0] = (_Float16)ra[p * 4 + 0][jj];
      hv[1] = (_Float16)ra[p * 4 + 1][jj];
      hv[2] = (_Float16)ra[p * 4 + 2][jj];
      hv[3] = (_Float16)ra[p * 4 + 3][jj];
      *(half4_t*)&Ads[(sw_chunk(n, kb) << 3) + kpar] = hv;
    }
  }
}

// ---- transpose-pattern staging, f16 source (phases 2/3) ---------------------
// thread owns 2 blocks of 4x8: rows k0..k0+3 = (rowg+h*16)*4.., cols colg*8..+7
__device__ __forceinline__ void tl_f16(const _Float16* __restrict__ src, half8_t rp[8],
                                       int colg, int rowg) {
#pragma unroll
  for (int h = 0; h < 2; ++h)
#pragma unroll
    for (int j = 0; j < 4; ++j)
      rp[h * 4 + j] = *(const half8_t*)&src[(((rowg + h * 16) << 2) + j) * DD + (colg << 3)];
}
__device__ __forceinline__ void tw_f16(_Float16* Ads, const half8_t rp[8],
                                       int colg, int rowg) {
#pragma unroll
  for (int h = 0; h < 2; ++h) {
    const int k0 = (rowg + h * 16) << 2;
    const int kb = k0 >> 3, kpar = k0 & 7;
#pragma unroll
    for (int jj = 0; jj < 8; ++jj) {
      const int n = (colg << 3) + jj;
      half4_t hv;
      hv[0] = rp[h * 4 + 0][jj]; hv[1] = rp[h * 4 + 1][jj];
      hv[2] = rp[h * 4 + 2][jj]; hv[3] = rp[h * 4 + 3][jj];
      *(half4_t*)&Ads[(sw_chunk(n, kb) << 3) + kpar] = hv;
    }
  }
}

// ---- Q-form epilogues: acc holds D = Z^T in C-layout, i.e. lane has 4
// CONTIGUOUS elements of row n of Z -> pure vector writes.
__device__ __forceinline__ void acc_store_f16(_Float16* __restrict__ dst,
                                              const f32x4 acc[4][4],
                                              int qr, int qc, int quad, int l16) {
#pragma unroll
  for (int tr = 0; tr < 4; ++tr)
#pragma unroll
    for (int tc = 0; tc < 4; ++tc) {
      int m0 = qr * 64 + tr * 16 + quad * 4;
      int n  = qc * 64 + tc * 16 + l16;
      half4_t hv;
      hv[0] = (_Float16)acc[tr][tc][0]; hv[1] = (_Float16)acc[tr][tc][1];
      hv[2] = (_Float16)acc[tr][tc][2]; hv[3] = (_Float16)acc[tr][tc][3];
      *(half4_t*)&dst[n * DD + m0] = hv;
    }
}
__device__ __forceinline__ void acc_to_bds(_Float16* Bds, const f32x4 acc[4][4],
                                           int qr, int qc, int quad, int l16) {
#pragma unroll
  for (int tr = 0; tr < 4; ++tr)
#pragma unroll
    for (int tc = 0; tc < 4; ++tc) {
      int m0 = qr * 64 + tr * 16 + quad * 4;
      int n  = qc * 64 + tc * 16 + l16;
      half4_t hv;
      hv[0] = (_Float16)acc[tr][tc][0]; hv[1] = (_Float16)acc[tr][tc][1];
      hv[2] = (_Float16)acc[tr][tc][2]; hv[3] = (_Float16)acc[tr][tc][3];
      *(half4_t*)&Bds[(sw_chunk(n, m0 >> 3) << 3) + (m0 & 7)] = hv;
    }
}

#define ZERO_ACC(acc)                                             \
  _Pragma("unroll") for (int tr = 0; tr < 4; ++tr)                \
  _Pragma("unroll") for (int tc = 0; tc < 4; ++tc) {              \
    f32x4 z = {0.f, 0.f, 0.f, 0.f}; acc[tr][tc] = z; }

// P slot: f16 normal-layout P_loc[t] lives in bytes [32768,65536) of out slot (b,t)
__device__ __forceinline__ _Float16* p_slot(float* out_all, int b, int t) {
  return (_Float16*)(out_all + (size_t)(b * SEQ + t) * MAT) + MAT;
}
__device__ __forceinline__ const _Float16* p_slot_c(const float* out_all, int b, int t) {
  return (const _Float16*)(out_all + (size_t)(b * SEQ + t) * MAT) + MAT;
}

// ---------------- phase 1: local chains (Q-form), emit P normal f16 ----------
// Q_i = A_i^T * Q_{i-1};  Aop = A_i^T (transpose-staged), Bop storage = P_{i-1} rows.
__global__ __launch_bounds__(256, 2) void k_phase1(const float* __restrict__ in,
                                                   float* __restrict__ out_all) {
  __shared__ __align__(16) _Float16 Ads[MAT];
  __shared__ __align__(16) _Float16 Bds[MAT];
  const int tid = threadIdx.x;
  const int b = blockIdx.x >> 4, c = blockIdx.x & 15;
  const int t0 = c * CL;
  const int wave = tid >> 6, lane = tid & 63;
  const int qr = wave >> 1, qc = wave & 1, quad = lane >> 4, l16 = lane & 15;
  const int colg = tid & 31, rowg0 = tid >> 5;

  const float* base = in + (size_t)(b * SEQ + t0) * MAT;

  // prologue: A_t0 direct (rb) + A_t0+1 transpose-pattern prefetch (ra)
  f32x4 rb[16];
  { const f32x4* s0 = (const f32x4*)base;
#pragma unroll
    for (int it = 0; it < 16; ++it) rb[it] = s0[tid + it * 256]; }
  f32x4 ra[16];
  tl_f32(base + MAT, ra, colg, rowg0);

  // Bds <- P_0 = A_t0 normal f16; also store P_0 to global
  { _Float16* g0 = p_slot(out_all, b, t0);
#pragma unroll
    for (int it = 0; it < 16; ++it) {
      int e0 = (tid + it * 256) << 2;
      int m = e0 >> 7, k0 = e0 & 127;
      half4_t hv;
      hv[0] = (_Float16)rb[it][0]; hv[1] = (_Float16)rb[it][1];
      hv[2] = (_Float16)rb[it][2]; hv[3] = (_Float16)rb[it][3];
      *(half4_t*)&Bds[(sw_chunk(m, k0 >> 3) << 3) + (k0 & 7)] = hv;
      *(half4_t*)&g0[e0] = hv;
    } }

  f32x4 acc[4][4];
  for (int i = 1; i < CL; ++i) {
    tw_f32(Ads, ra, colg, rowg0);                        // A_i^T -> Ads
    if (i < CL - 1) tl_f32(base + (size_t)(i + 1) * MAT, ra, colg, rowg0);  // prefetch
    barrier_lgkm();                                      // Ads + Bds visible
    ZERO_ACC(acc);
    mm128(Ads, Bds, acc, qr, qc, quad, l16);             // acc = P_i^T (C-layout)
    acc_store_f16(p_slot(out_all, b, t0 + i), acc, qr, qc, quad, l16);  // P_i -> global
    barrier_only();                                      // everyone done reading LDS
    if (i < CL - 1) acc_to_bds(Bds, acc, qr, qc, quad, l16);            // P_i -> Bop
  }
}

// ---------------- phase 2: scan chunk totals (Q-form) ------------------------
// S_c = S_{c-1} * T_c;  Aop = T_c^T (transpose-staged from P slot), Bop = S_{c-1} rows.
__global__ __launch_bounds__(256, 2) void k_phase2(const float* __restrict__ out_all,
                                                   _Float16* __restrict__ Sbuf,
                                                   float* __restrict__ out_x) {
  __shared__ __align__(16) _Float16 Ads[MAT];
  __shared__ __align__(16) _Float16 Bds[MAT];
  const int tid = threadIdx.x, b = blockIdx.x;
  const int wave = tid >> 6, lane = tid & 63;
  const int qr = wave >> 1, qc = wave & 1, quad = lane >> 4, l16 = lane & 15;
  const int colg = tid & 15, rowg = tid >> 4;

  // prologue: S_0 = T_0 -> Bds + Sbuf[0]; prefetch T_1
  { const uint4* s = (const uint4*)p_slot_c(out_all, b, CL - 1);
    uint4* sb0 = (uint4*)(Sbuf + (size_t)b * NCH * MAT);
#pragma unroll
    for (int it = 0; it < 8; ++it) {
      int idx = tid + it * 256;
      uint4 v = s[idx];
      *(uint4*)&Bds[sw_chunk(idx >> 4, idx & 15) << 3] = v;
      sb0[idx] = v;
    } }
  half8_t rp[8];
  tl_f16(p_slot_c(out_all, b, 2 * CL - 1), rp, colg, rowg);

  f32x4 acc[4][4];
  for (int cc = 1; cc < NCH; ++cc) {
    tw_f16(Ads, rp, colg, rowg);                         // T_cc^T -> Ads
    if (cc < NCH - 1)
      tl_f16(p_slot_c(out_all, b, (cc + 2) * CL - 1), rp, colg, rowg);
    barrier_lgkm();
    ZERO_ACC(acc);
    mm128(Ads, Bds, acc, qr, qc, quad, l16);             // acc = S_cc^T
    if (cc < NCH - 1) {
      acc_store_f16(Sbuf + ((size_t)b * NCH + cc) * MAT, acc, qr, qc, quad, l16);
    } else {                                             // S_15 = full product -> x
      float* xo = out_x + (size_t)b * MAT;
#pragma unroll
      for (int tr = 0; tr < 4; ++tr)
#pragma unroll
        for (int tc = 0; tc < 4; ++tc) {
          int m0 = qr * 64 + tr * 16 + quad * 4;
          int n  = qc * 64 + tc * 16 + l16;
          *(f32x4*)&xo[n * DD + m0] = acc[tr][tc];
        }
    }
    barrier_only();
    if (cc < NCH - 1) acc_to_bds(Bds, acc, qr, qc, quad, l16);
  }
}

// ---------------- phase 3: out[t] = S_{c-1} * P_loc[t] (Q-form) --------------
// X^T = P^T * S^T;  Aop = P^T (transpose-staged), Bop = S rows (staged once).
// acc rows of X contiguous -> direct f32x4 stores.
__global__ __launch_bounds__(256, 2) void k_phase3(float* __restrict__ out_all,
                                                   const _Float16* __restrict__ Sbuf) {
  __shared__ __align__(16) _Float16 Ads[MAT];
  __shared__ __align__(16) _Float16 Bds[MAT];
  const int tid = threadIdx.x;
  const int b = blockIdx.x >> 4, c = blockIdx.x & 15;
  const int t0 = c * CL;
  const int wave = tid >> 6, lane = tid & 63;
  const int qr = wave >> 1, qc = wave & 1, quad = lane >> 4, l16 = lane & 15;
  const int colg = tid & 15, rowg = tid >> 4;

  if (c == 0) {                                          // S = I
    uint4 z; z.x = z.y = z.z = z.w = 0u;
#pragma unroll
    for (int it = 0; it < 8; ++it) *(uint4*)&Bds[(tid + it * 256) << 3] = z;
    barrier_lgkm();
    if (tid < DD) Bds[sw_off(tid, tid)] = (_Float16)1.0f;
  } else {
    const uint4* s = (const uint4*)(Sbuf + ((size_t)b * NCH + (c - 1)) * MAT);
#pragma unroll
    for (int it = 0; it < 8; ++it) {
      int idx = tid + it * 256;
      *(uint4*)&Bds[sw_chunk(idx >> 4, idx & 15) << 3] = s[idx];
    }
  }
  half8_t rp[8];
  tl_f16(p_slot_c(out_all, b, t0), rp, colg, rowg);      // own P, read-before-overwrite

  f32x4 acc[4][4];
  for (int i = 0; i < CL; ++i) {
    const int t = t0 + i;
    tw_f16(Ads, rp, colg, rowg);                         // P[t]^T -> Ads
    if (i < CL - 1)
      tl_f16(p_slot_c(out_all, b, t + 1), rp, colg, rowg);  // prefetch next P
    barrier_lgkm();
    ZERO_ACC(acc);
    mm128(Ads, Bds, acc, qr, qc, quad, l16);             // acc = X^T
    float* slot = out_all + (size_t)(b * SEQ + t) * MAT;
#pragma unroll
    for (int tr = 0; tr < 4; ++tr)
#pragma unroll
      for (int tc = 0; tc < 4; ++tc) {
        int m0 = qr * 64 + tr * 16 + quad * 4;
        int n  = qc * 64 + tc * 16 + l16;
        *(f32x4*)&slot[n * DD + m0] = acc[tr][tc];       // X normal fp32, vectorized
      }
    barrier_only();                                      // all waves done with Ads
  }
}

extern "C" void kernel_launch(void* const* d_in, const int* in_sizes, int n_in,
                              void* d_out, int out_size, void* d_ws, size_t ws_size,
                              hipStream_t stream) {
  const float* in = (const float*)d_in[0];
  float* out_x   = (float*)d_out;                 // [32,128,128]
  float* out_all = out_x + (size_t)BSZ * MAT;     // [32,256,128,128]
  _Float16* Sbuf = (_Float16*)d_ws;               // 32*16 matrices f16 = 16 MiB

  k_phase1<<<dim3(BSZ * NCH), dim3(256), 0, stream>>>(in, out_all);
  k_phase2<<<dim3(BSZ), dim3(256), 0, stream>>>((const float*)out_all, Sbuf, out_x);
  k_phase3<<<dim3(BSZ * NCH), dim3(256), 0, stream>>>(out_all, Sbuf);
}